// Round 1
// baseline (339.503 us; speedup 1.0000x reference)
//
#include <hip/hip_runtime.h>
#include <hip/hip_bf16.h>

// Problem constants: B=4, T=4096, C=1024, H=64
#define Bn 4
#define Tn 4096
#define Cn 1024
#define Hn 64

typedef __bf16 bf16_t;
typedef __bf16 bf16x8 __attribute__((ext_vector_type(8)));
typedef float f32x4 __attribute__((ext_vector_type(4)));

// Workspace layout (bf16 elements):
//   WT  [192][1024]        -> 196608 el
//   q   [B*T][64]          -> 1048576 el
//   k   [B*T][64]          -> 1048576 el
//   vt  [B][64][T]         -> 1048576 el   (v transposed for PV B-frag reads)
#define WT_OFF 0
#define Q_OFF  196608
#define K_OFF  (196608 + 1048576)
#define VT_OFF (196608 + 2 * 1048576)

// ---------------------------------------------------------------------------
// Kernel 0: build WT[n][k] = W_sel[k][n&63] as bf16. n in [0,192), k in [0,1024)
// ---------------------------------------------------------------------------
__global__ void wt_kernel(const float* __restrict__ Wq, const float* __restrict__ Wk,
                          const float* __restrict__ Wv, bf16_t* __restrict__ WT) {
    int idx = blockIdx.x * 256 + threadIdx.x;   // idx = k*192 + n  (coalesced reads)
    int k = idx / 192;
    int n = idx - k * 192;
    const float* W = (n < 64) ? Wq : (n < 128) ? Wk : Wv;
    int nn = n & 63;
    WT[(size_t)n * 1024 + k] = (bf16_t)W[(size_t)k * 64 + nn];
}

// ---------------------------------------------------------------------------
// Kernel 1: QKV projection. Grid: 256 blocks (64-row M-tiles), 256 thr/block.
// Each wave computes n-subtiles {3w..3w+2} over all 64 rows (4 row-tiles).
// ---------------------------------------------------------------------------
__launch_bounds__(256)
__global__ void proj_kernel(const float* __restrict__ x, const bf16_t* __restrict__ WT,
                            bf16_t* __restrict__ q, bf16_t* __restrict__ kmat,
                            bf16_t* __restrict__ vt) {
    __shared__ bf16_t xs[64][72];    // +8 el pad keeps 16B align, spreads banks
    __shared__ bf16_t ws[192][72];

    const int tid  = threadIdx.x;
    const int wave = tid >> 6;
    const int lane = tid & 63;
    const int l15  = lane & 15;
    const int quad = lane >> 4;
    const int m0   = blockIdx.x * 64;

    f32x4 acc[3][4];
#pragma unroll
    for (int nn = 0; nn < 3; ++nn)
#pragma unroll
        for (int rt = 0; rt < 4; ++rt)
            acc[nn][rt] = (f32x4){0.f, 0.f, 0.f, 0.f};

    for (int k0 = 0; k0 < Cn; k0 += 64) {
        __syncthreads();   // protect LDS from previous iteration's readers
        // stage x chunk [64 rows][64 k] fp32 -> bf16
#pragma unroll
        for (int i = 0; i < 4; ++i) {
            int idx = i * 256 + tid;           // 0..1023
            int r  = idx >> 4;
            int c4 = idx & 15;
            float4 v = *(const float4*)(x + (size_t)(m0 + r) * Cn + k0 + c4 * 4);
            bf16_t* dst = &xs[r][c4 * 4];
            dst[0] = (bf16_t)v.x; dst[1] = (bf16_t)v.y;
            dst[2] = (bf16_t)v.z; dst[3] = (bf16_t)v.w;
        }
        // stage WT chunk [192 n][64 k] bf16 (16B vector copies)
#pragma unroll
        for (int i = 0; i < 6; ++i) {
            int idx = i * 256 + tid;           // 0..1535
            int n  = idx >> 3;
            int c8 = idx & 7;
            uint4 v = *(const uint4*)(WT + (size_t)n * 1024 + k0 + c8 * 8);
            *(uint4*)&ws[n][c8 * 8] = v;
        }
        __syncthreads();
#pragma unroll
        for (int kk = 0; kk < 64; kk += 32) {
            bf16x8 af[4];
#pragma unroll
            for (int rt = 0; rt < 4; ++rt)
                af[rt] = *(const bf16x8*)&xs[rt * 16 + l15][kk + quad * 8];
#pragma unroll
            for (int nn = 0; nn < 3; ++nn) {
                bf16x8 bfr = *(const bf16x8*)&ws[(wave * 3 + nn) * 16 + l15][kk + quad * 8];
#pragma unroll
                for (int rt = 0; rt < 4; ++rt)
                    acc[nn][rt] = __builtin_amdgcn_mfma_f32_16x16x32_bf16(af[rt], bfr, acc[nn][rt], 0, 0, 0);
            }
        }
    }
    // epilogue: C/D layout col=lane&15, row=quad*4+reg
#pragma unroll
    for (int nn = 0; nn < 3; ++nn) {
        int n = (wave * 3 + nn) * 16 + l15;    // 0..191
#pragma unroll
        for (int rt = 0; rt < 4; ++rt) {
#pragma unroll
            for (int r = 0; r < 4; ++r) {
                int row = m0 + rt * 16 + quad * 4 + r;   // global 0..16383
                float v = acc[nn][rt][r];
                if (n < 64) {
                    q[(size_t)row * Hn + n] = (bf16_t)v;
                } else if (n < 128) {
                    kmat[(size_t)row * Hn + (n - 64)] = (bf16_t)v;
                } else {
                    int b  = row >> 12;
                    int tr = row & (Tn - 1);
                    vt[((size_t)b * Hn + (n - 128)) * Tn + tr] = (bf16_t)v;
                }
            }
        }
    }
}

// ---------------------------------------------------------------------------
// Kernel 2: causal flash attention. Grid (T/64, B), 256 thr. Wave w owns q-rows
// [16w,16w+16). Online softmax; P goes C-layout -> LDS -> A-layout for PV.
// ---------------------------------------------------------------------------
__launch_bounds__(256)
__global__ void attn_kernel(const bf16_t* __restrict__ q, const bf16_t* __restrict__ kmat,
                            const bf16_t* __restrict__ vt, float* __restrict__ out) {
    __shared__ bf16_t p_lds[4][16][72];

    const int tid  = threadIdx.x;
    const int wave = tid >> 6;
    const int lane = tid & 63;
    const int l15  = lane & 15;
    const int quad = lane >> 4;
    const int tile = blockIdx.x;   // 0..63
    const int b    = blockIdx.y;   // 0..3
    const int q0   = tile * 64;

    // Q A-fragments, loaded once: m = lane&15, k = quad*8+j
    size_t qbase = ((size_t)b * Tn + q0 + wave * 16 + l15) * Hn;
    bf16x8 qf0 = *(const bf16x8*)(q + qbase + quad * 8);
    bf16x8 qf1 = *(const bf16x8*)(q + qbase + 32 + quad * 8);

    f32x4 acc_o[4];
#pragma unroll
    for (int t = 0; t < 4; ++t) acc_o[t] = (f32x4){0.f, 0.f, 0.f, 0.f};
    float m2[4], lsum[4];
#pragma unroll
    for (int r = 0; r < 4; ++r) { m2[r] = -INFINITY; lsum[r] = 0.f; }

    const float sc2 = 0.125f * 1.44269504088896340736f;  // scale * log2(e)

    for (int j = 0; j <= tile; ++j) {
        const int s0 = j * 64;
        // ---- S = Q K^T over H=64 (2 MFMAs per 16x16 n-subtile) ----
        f32x4 accs[4];
#pragma unroll
        for (int t = 0; t < 4; ++t) accs[t] = (f32x4){0.f, 0.f, 0.f, 0.f};
#pragma unroll
        for (int t = 0; t < 4; ++t) {
            size_t kbase = ((size_t)b * Tn + s0 + t * 16 + l15) * Hn;
            bf16x8 kf0 = *(const bf16x8*)(kmat + kbase + quad * 8);
            bf16x8 kf1 = *(const bf16x8*)(kmat + kbase + 32 + quad * 8);
            accs[t] = __builtin_amdgcn_mfma_f32_16x16x32_bf16(qf0, kf0, accs[t], 0, 0, 0);
            accs[t] = __builtin_amdgcn_mfma_f32_16x16x32_bf16(qf1, kf1, accs[t], 0, 0, 0);
        }
        // ---- scale (folded log2e) + causal mask ----
        float ps[4][4];
        const bool diag = (j == tile);
        const int rowb = q0 + wave * 16 + quad * 4;
#pragma unroll
        for (int t = 0; t < 4; ++t) {
            int col = s0 + t * 16 + l15;
#pragma unroll
            for (int r = 0; r < 4; ++r) {
                float sv = accs[t][r] * sc2;
                if (diag && col > rowb + r) sv = -INFINITY;
                ps[t][r] = sv;
            }
        }
        // ---- row max (4 subtiles in-lane, then 16-lane shfl reduce) ----
        float alpha[4], psum[4];
#pragma unroll
        for (int r = 0; r < 4; ++r) {
            float v = fmaxf(fmaxf(ps[0][r], ps[1][r]), fmaxf(ps[2][r], ps[3][r]));
            v = fmaxf(v, __shfl_xor(v, 1));
            v = fmaxf(v, __shfl_xor(v, 2));
            v = fmaxf(v, __shfl_xor(v, 4));
            v = fmaxf(v, __shfl_xor(v, 8));
            float mn = fmaxf(m2[r], v);
            alpha[r] = exp2f(m2[r] - mn);   // m2=-inf first iter -> 0
            m2[r] = mn;
            psum[r] = 0.f;
        }
        __syncthreads();   // prior PV reads of p_lds done
        // ---- P = exp2(s2 - m2), write to LDS in C-layout ----
#pragma unroll
        for (int t = 0; t < 4; ++t) {
#pragma unroll
            for (int r = 0; r < 4; ++r) {
                float p = exp2f(ps[t][r] - m2[r]);
                psum[r] += p;
                p_lds[wave][quad * 4 + r][t * 16 + l15] = (bf16_t)p;
            }
        }
        // ---- l update + O rescale ----
#pragma unroll
        for (int r = 0; r < 4; ++r) {
            float v = psum[r];
            v += __shfl_xor(v, 1);
            v += __shfl_xor(v, 2);
            v += __shfl_xor(v, 4);
            v += __shfl_xor(v, 8);
            lsum[r] = lsum[r] * alpha[r] + v;
        }
#pragma unroll
        for (int t = 0; t < 4; ++t)
#pragma unroll
            for (int r = 0; r < 4; ++r)
                acc_o[t][r] *= alpha[r];
        __syncthreads();   // p_lds writes visible
        // ---- O += P V  (P A-frags from LDS, V B-frags from vt) ----
#pragma unroll
        for (int kk2 = 0; kk2 < 64; kk2 += 32) {
            bf16x8 pf = *(const bf16x8*)&p_lds[wave][l15][kk2 + quad * 8];
#pragma unroll
            for (int t2 = 0; t2 < 4; ++t2) {
                size_t vbase = ((size_t)b * Hn + t2 * 16 + l15) * Tn + s0 + kk2 + quad * 8;
                bf16x8 vf = *(const bf16x8*)(vt + vbase);
                acc_o[t2] = __builtin_amdgcn_mfma_f32_16x16x32_bf16(pf, vf, acc_o[t2], 0, 0, 0);
            }
        }
    }
    // ---- epilogue: normalize and store fp32 ----
#pragma unroll
    for (int t2 = 0; t2 < 4; ++t2) {
#pragma unroll
        for (int r = 0; r < 4; ++r) {
            size_t row = (size_t)b * Tn + q0 + wave * 16 + quad * 4 + r;
            out[row * Hn + t2 * 16 + l15] = acc_o[t2][r] / lsum[r];
        }
    }
}

// ---------------------------------------------------------------------------
extern "C" void kernel_launch(void* const* d_in, const int* in_sizes, int n_in,
                              void* d_out, int out_size, void* d_ws, size_t ws_size,
                              hipStream_t stream) {
    const float* x  = (const float*)d_in[0];
    const float* Wq = (const float*)d_in[1];
    const float* Wk = (const float*)d_in[2];
    const float* Wv = (const float*)d_in[3];
    float* out = (float*)d_out;

    bf16_t* ws = (bf16_t*)d_ws;
    bf16_t* WT = ws + WT_OFF;
    bf16_t* qb = ws + Q_OFF;
    bf16_t* kb = ws + K_OFF;
    bf16_t* vt = ws + VT_OFF;

    wt_kernel<<<dim3(192 * 1024 / 256), dim3(256), 0, stream>>>(Wq, Wk, Wv, WT);
    proj_kernel<<<dim3((Bn * Tn) / 64), dim3(256), 0, stream>>>(x, WT, qb, kb, vt);
    attn_kernel<<<dim3(Tn / 64, Bn), dim3(256), 0, stream>>>(qb, kb, vt, out);
}

// Round 2
// 188.546 us; speedup vs baseline: 1.8006x; 1.8006x over previous
//
#include <hip/hip_runtime.h>
#include <hip/hip_bf16.h>
#include <math.h>

// Problem constants: B=4, T=4096, C=1024, H=64
#define Bn 4
#define Tn 4096
#define Cn 1024
#define Hn 64

typedef __bf16 bf16_t;
typedef __bf16 bf16x8 __attribute__((ext_vector_type(8)));
typedef float f32x4 __attribute__((ext_vector_type(4)));

// bf16 workspace layout (elements)
#define WT_OFF 0
#define Q_OFF  196608
#define K_OFF  (Q_OFF + 1048576)
#define VT_OFF (K_OFF + 1048576)
#define BF16_WS_ELEMS (VT_OFF + 1048576)   // 3,342,336 el -> 6,684,672 bytes

// ---------------------------------------------------------------------------
// Kernel 0: WT[n][k] = W_sel[k][n&63] bf16. n in [0,192), k in [0,1024)
// ---------------------------------------------------------------------------
__global__ void wt_kernel(const float* __restrict__ Wq, const float* __restrict__ Wk,
                          const float* __restrict__ Wv, bf16_t* __restrict__ WT) {
    int idx = blockIdx.x * 256 + threadIdx.x;   // idx = k*192 + n
    int k = idx / 192;
    int n = idx - k * 192;
    const float* W = (n < 64) ? Wq : (n < 128) ? Wk : Wv;
    int nn = n & 63;
    WT[(size_t)n * 1024 + k] = (bf16_t)W[(size_t)k * 64 + nn];
}

// ---------------------------------------------------------------------------
// Kernel 1: QKV projection. 512 blocks (32-row M-tiles => 2 blocks/CU), 256 thr.
// ---------------------------------------------------------------------------
__launch_bounds__(256)
__global__ void proj_kernel(const float* __restrict__ x, const bf16_t* __restrict__ WT,
                            bf16_t* __restrict__ q, bf16_t* __restrict__ kmat,
                            bf16_t* __restrict__ vt) {
    __shared__ bf16_t xs[32][72];
    __shared__ bf16_t ws[192][72];

    const int tid  = threadIdx.x;
    const int wave = tid >> 6;
    const int lane = tid & 63;
    const int l15  = lane & 15;
    const int quad = lane >> 4;
    const int m0   = blockIdx.x * 32;

    f32x4 acc[3][2];
#pragma unroll
    for (int nn = 0; nn < 3; ++nn)
#pragma unroll
        for (int rt = 0; rt < 2; ++rt)
            acc[nn][rt] = (f32x4){0.f, 0.f, 0.f, 0.f};

    for (int k0 = 0; k0 < Cn; k0 += 64) {
        __syncthreads();
        // stage x chunk [32 rows][64 k] fp32 -> bf16
#pragma unroll
        for (int i = 0; i < 2; ++i) {
            int idx = i * 256 + tid;           // 0..511
            int r  = idx >> 4;
            int c4 = idx & 15;
            float4 v = *(const float4*)(x + (size_t)(m0 + r) * Cn + k0 + c4 * 4);
            bf16_t* dst = &xs[r][c4 * 4];
            dst[0] = (bf16_t)v.x; dst[1] = (bf16_t)v.y;
            dst[2] = (bf16_t)v.z; dst[3] = (bf16_t)v.w;
        }
        // stage WT chunk [192 n][64 k] bf16
#pragma unroll
        for (int i = 0; i < 6; ++i) {
            int idx = i * 256 + tid;           // 0..1535
            int n  = idx >> 3;
            int c8 = idx & 7;
            *(uint4*)&ws[n][c8 * 8] = *(const uint4*)(WT + (size_t)n * 1024 + k0 + c8 * 8);
        }
        __syncthreads();
#pragma unroll
        for (int kk = 0; kk < 64; kk += 32) {
            bf16x8 af[2];
#pragma unroll
            for (int rt = 0; rt < 2; ++rt)
                af[rt] = *(const bf16x8*)&xs[rt * 16 + l15][kk + quad * 8];
#pragma unroll
            for (int nn = 0; nn < 3; ++nn) {
                bf16x8 bfr = *(const bf16x8*)&ws[(wave * 3 + nn) * 16 + l15][kk + quad * 8];
#pragma unroll
                for (int rt = 0; rt < 2; ++rt)
                    acc[nn][rt] = __builtin_amdgcn_mfma_f32_16x16x32_bf16(af[rt], bfr, acc[nn][rt], 0, 0, 0);
            }
        }
    }
    // epilogue: C/D layout col=lane&15, row=quad*4+reg
#pragma unroll
    for (int nn = 0; nn < 3; ++nn) {
        int n = (wave * 3 + nn) * 16 + l15;    // 0..191
#pragma unroll
        for (int rt = 0; rt < 2; ++rt) {
#pragma unroll
            for (int r = 0; r < 4; ++r) {
                int row = m0 + rt * 16 + quad * 4 + r;
                float v = acc[nn][rt][r];
                if (n < 64) {
                    q[(size_t)row * Hn + n] = (bf16_t)v;
                } else if (n < 128) {
                    kmat[(size_t)row * Hn + (n - 64)] = (bf16_t)v;
                } else {
                    int b  = row >> 12;
                    int tr = row & (Tn - 1);
                    vt[((size_t)b * Hn + (n - 128)) * Tn + tr] = (bf16_t)v;
                }
            }
        }
    }
}

// ---------------------------------------------------------------------------
// Kernel 2: split-KV causal flash attention (partial). Grid (NSMAX, 64, B).
// Block handles q-tile t (64 rows), KV units [split*UPS, min(+UPS, t+1)).
// K/V tiles staged in LDS once per unit (shared by all 4 waves).
// p_lds is wave-private: no barriers around it.
// ---------------------------------------------------------------------------
__launch_bounds__(256)
__global__ void attn_part(const bf16_t* __restrict__ q, const bf16_t* __restrict__ kmat,
                          const bf16_t* __restrict__ vt, float* __restrict__ Opart,
                          float* __restrict__ mpart, float* __restrict__ lpart,
                          int UPS, int NSMAX) {
    __shared__ bf16_t ks[64][72];
    __shared__ bf16_t vls[64][72];
    __shared__ bf16_t p_lds[4][16][72];

    const int tid  = threadIdx.x;
    const int wave = tid >> 6;
    const int lane = tid & 63;
    const int l15  = lane & 15;
    const int quad = lane >> 4;
    const int split = blockIdx.x;
    const int t     = blockIdx.y;   // q-tile 0..63
    const int b     = blockIdx.z;

    const int nsplit = t / UPS + 1;
    if (split >= nsplit) return;
    const int u0 = split * UPS;
    const int u1 = min(u0 + UPS, t + 1);
    const int q0 = t * 64;

    // Q A-frags: m=lane&15, k=quad*8+j
    size_t qbase = ((size_t)b * Tn + q0 + wave * 16 + l15) * Hn;
    bf16x8 qf0 = *(const bf16x8*)(q + qbase + quad * 8);
    bf16x8 qf1 = *(const bf16x8*)(q + qbase + 32 + quad * 8);

    f32x4 acc_o[4];
#pragma unroll
    for (int i = 0; i < 4; ++i) acc_o[i] = (f32x4){0.f, 0.f, 0.f, 0.f};
    float m2[4], lsum[4];
#pragma unroll
    for (int r = 0; r < 4; ++r) { m2[r] = -INFINITY; lsum[r] = 0.f; }

    const float sc2 = 0.125f * 1.44269504088896340736f;  // scale * log2(e)

    for (int u = u0; u < u1; ++u) {
        const int s0 = u * 64;
        __syncthreads();   // prev unit's LDS reads done
        // stage K[64][64] and V^T[64 h][64 s] tiles (16B chunks, 2 each/thread)
#pragma unroll
        for (int i = 0; i < 2; ++i) {
            int idx = i * 256 + tid;    // 0..511
            int row = idx >> 3;
            int c8  = idx & 7;
            *(uint4*)&ks[row][c8 * 8]  = *(const uint4*)(kmat + ((size_t)b * Tn + s0 + row) * Hn + c8 * 8);
            *(uint4*)&vls[row][c8 * 8] = *(const uint4*)(vt + ((size_t)b * Hn + row) * Tn + s0 + c8 * 8);
        }
        __syncthreads();

        // ---- S = Q K^T ----
        f32x4 accs[4];
#pragma unroll
        for (int ts = 0; ts < 4; ++ts) accs[ts] = (f32x4){0.f, 0.f, 0.f, 0.f};
#pragma unroll
        for (int ts = 0; ts < 4; ++ts) {
            bf16x8 kf0 = *(const bf16x8*)&ks[ts * 16 + l15][quad * 8];
            bf16x8 kf1 = *(const bf16x8*)&ks[ts * 16 + l15][32 + quad * 8];
            accs[ts] = __builtin_amdgcn_mfma_f32_16x16x32_bf16(qf0, kf0, accs[ts], 0, 0, 0);
            accs[ts] = __builtin_amdgcn_mfma_f32_16x16x32_bf16(qf1, kf1, accs[ts], 0, 0, 0);
        }
        // ---- scale + causal mask (only diag unit) ----
        float ps[4][4];
        const bool diag = (u == t);
        const int rowb = q0 + wave * 16 + quad * 4;
#pragma unroll
        for (int ts = 0; ts < 4; ++ts) {
            int col = s0 + ts * 16 + l15;
#pragma unroll
            for (int r = 0; r < 4; ++r) {
                float sv = accs[ts][r] * sc2;
                if (diag && col > rowb + r) sv = -INFINITY;
                ps[ts][r] = sv;
            }
        }
        // ---- row max ----
        float alpha[4], psum[4];
#pragma unroll
        for (int r = 0; r < 4; ++r) {
            float v = fmaxf(fmaxf(ps[0][r], ps[1][r]), fmaxf(ps[2][r], ps[3][r]));
            v = fmaxf(v, __shfl_xor(v, 1));
            v = fmaxf(v, __shfl_xor(v, 2));
            v = fmaxf(v, __shfl_xor(v, 4));
            v = fmaxf(v, __shfl_xor(v, 8));
            float mn = fmaxf(m2[r], v);
            alpha[r] = exp2f(m2[r] - mn);
            m2[r] = mn;
            psum[r] = 0.f;
        }
        // ---- P to LDS (wave-private region; same-wave lgkm ordering suffices) ----
#pragma unroll
        for (int ts = 0; ts < 4; ++ts) {
#pragma unroll
            for (int r = 0; r < 4; ++r) {
                float p = exp2f(ps[ts][r] - m2[r]);
                psum[r] += p;
                p_lds[wave][quad * 4 + r][ts * 16 + l15] = (bf16_t)p;
            }
        }
        // ---- l update + O rescale ----
#pragma unroll
        for (int r = 0; r < 4; ++r) {
            float v = psum[r];
            v += __shfl_xor(v, 1);
            v += __shfl_xor(v, 2);
            v += __shfl_xor(v, 4);
            v += __shfl_xor(v, 8);
            lsum[r] = lsum[r] * alpha[r] + v;
        }
#pragma unroll
        for (int ts = 0; ts < 4; ++ts)
#pragma unroll
            for (int r = 0; r < 4; ++r)
                acc_o[ts][r] *= alpha[r];
        // ---- O += P V ----
#pragma unroll
        for (int kk2 = 0; kk2 < 64; kk2 += 32) {
            bf16x8 pf = *(const bf16x8*)&p_lds[wave][l15][kk2 + quad * 8];
#pragma unroll
            for (int t2 = 0; t2 < 4; ++t2) {
                bf16x8 vf = *(const bf16x8*)&vls[t2 * 16 + l15][kk2 + quad * 8];
                acc_o[t2] = __builtin_amdgcn_mfma_f32_16x16x32_bf16(pf, vf, acc_o[t2], 0, 0, 0);
            }
        }
    }
    // ---- write partials (unnormalized O, m, l) ----
    size_t pbase = ((size_t)(b * 64 + t) * NSMAX + split) * 4096;
#pragma unroll
    for (int t2 = 0; t2 < 4; ++t2)
#pragma unroll
        for (int r = 0; r < 4; ++r)
            Opart[pbase + (size_t)(wave * 16 + quad * 4 + r) * 64 + t2 * 16 + l15] = acc_o[t2][r];
    if (l15 == 0) {
        size_t mbase = ((size_t)(b * 64 + t) * NSMAX + split) * 64;
#pragma unroll
        for (int r = 0; r < 4; ++r) {
            mpart[mbase + wave * 16 + quad * 4 + r] = m2[r];
            lpart[mbase + wave * 16 + quad * 4 + r] = lsum[r];
        }
    }
}

// ---------------------------------------------------------------------------
// Kernel 3: combine partials. Grid (64, B), 256 thr. thread: row=tid/4, 16 cols.
// ---------------------------------------------------------------------------
__launch_bounds__(256)
__global__ void combine_kernel(const float* __restrict__ Opart, const float* __restrict__ mpart,
                               const float* __restrict__ lpart, float* __restrict__ out,
                               int UPS, int NSMAX) {
    const int t = blockIdx.x;
    const int b = blockIdx.y;
    const int ns = t / UPS + 1;
    const int tid = threadIdx.x;
    const int row = tid >> 2;
    const int cg  = tid & 3;

    size_t pbase = (size_t)(b * 64 + t) * NSMAX * 4096;
    size_t mbase = (size_t)(b * 64 + t) * NSMAX * 64;

    float ms[8], ls[8];
    float M = -INFINITY;
    for (int s = 0; s < ns; ++s) {
        ms[s] = mpart[mbase + s * 64 + row];
        ls[s] = lpart[mbase + s * 64 + row];
        M = fmaxf(M, ms[s]);
    }
    float L = 0.f;
    float4 o[4];
#pragma unroll
    for (int i = 0; i < 4; ++i) o[i] = (float4){0.f, 0.f, 0.f, 0.f};
    for (int s = 0; s < ns; ++s) {
        float w = exp2f(ms[s] - M);
        L += w * ls[s];
        const float4* src = (const float4*)(Opart + pbase + (size_t)s * 4096 + (size_t)row * 64 + cg * 16);
#pragma unroll
        for (int i = 0; i < 4; ++i) {
            float4 v = src[i];
            o[i].x += w * v.x; o[i].y += w * v.y; o[i].z += w * v.z; o[i].w += w * v.w;
        }
    }
    float inv = 1.f / L;
    float* dst = out + ((size_t)b * Tn + t * 64 + row) * Hn + cg * 16;
#pragma unroll
    for (int i = 0; i < 4; ++i) {
        float4 v = o[i];
        v.x *= inv; v.y *= inv; v.z *= inv; v.w *= inv;
        ((float4*)dst)[i] = v;
    }
}

// ---------------------------------------------------------------------------
extern "C" void kernel_launch(void* const* d_in, const int* in_sizes, int n_in,
                              void* d_out, int out_size, void* d_ws, size_t ws_size,
                              hipStream_t stream) {
    const float* x  = (const float*)d_in[0];
    const float* Wq = (const float*)d_in[1];
    const float* Wk = (const float*)d_in[2];
    const float* Wv = (const float*)d_in[3];
    float* out = (float*)d_out;

    bf16_t* wsb = (bf16_t*)d_ws;
    bf16_t* WT = wsb + WT_OFF;
    bf16_t* qb = wsb + Q_OFF;
    bf16_t* kb = wsb + K_OFF;
    bf16_t* vt = wsb + VT_OFF;

    const size_t base = (size_t)BF16_WS_ELEMS * 2;   // bytes used by bf16 region
    int NSMAX = 8;
    while (NSMAX > 1) {
        size_t need = base + (size_t)NSMAX * Bn * 64 * 4096 * 4      // Opart
                           + (size_t)NSMAX * Bn * 64 * 64 * 4 * 2;   // mpart+lpart
        if (need <= ws_size) break;
        NSMAX >>= 1;
    }
    const int UPS = 64 / NSMAX;

    float* Opart = (float*)((char*)d_ws + base);
    float* mpart = Opart + (size_t)NSMAX * Bn * 64 * 4096;
    float* lpart = mpart + (size_t)NSMAX * Bn * 64 * 64;

    wt_kernel<<<dim3(192 * 1024 / 256), dim3(256), 0, stream>>>(Wq, Wk, Wv, WT);
    proj_kernel<<<dim3((Bn * Tn) / 32), dim3(256), 0, stream>>>(x, WT, qb, kb, vt);
    attn_part<<<dim3(NSMAX, Tn / 64, Bn), dim3(256), 0, stream>>>(qb, kb, vt, Opart, mpart, lpart, UPS, NSMAX);
    combine_kernel<<<dim3(Tn / 64, Bn), dim3(256), 0, stream>>>(Opart, mpart, lpart, out, UPS, NSMAX);
}